// Round 1
// baseline (132.607 us; speedup 1.0000x reference)
//
#include <hip/hip_runtime.h>

#define N 4096
#define EPS 1e-8f

// ---------------------------------------------------------------------------
// Kernel 1: partial repulsive forces.
// grid = (4, nbj), block = 256. Each thread owns MI=4 agents (i) in registers
// (ILP to hide rsqrt/exp latency at 2 waves/SIMD). j is wave-uniform ->
// scalar s_load for the j position; zero VMEM pressure in the inner loop.
// part layout: [nbj][N][2] floats in d_ws.
// ---------------------------------------------------------------------------
__global__ __launch_bounds__(256) void rep_partial(const float* __restrict__ state,
                                                   float* __restrict__ part,
                                                   int jchunk) {
    const int tid = threadIdx.x;
    const int ib  = blockIdx.x;   // 0..3
    const int jb  = blockIdx.y;   // 0..nbj-1

    float xi[4], yi[4], fx[4], fy[4];
#pragma unroll
    for (int m = 0; m < 4; ++m) {
        const int i = ib * 1024 + m * 256 + tid;
        xi[m] = state[i * 4 + 0];
        yi[m] = state[i * 4 + 1];
        fx[m] = 0.f;
        fy[m] = 0.f;
    }

    // mag/dist = ALPHA * exp((2R - d)/BETTA) / d
    //          = exp2(C0 - C1*d) * (1/d),  C1 = log2e/BETTA, C0 = 2R*C1 + log2(ALPHA)
    const float C1 = 1.44269504088896340736f / 0.71f;
    const float C0 = 0.6f * C1 + 3.41414351f;   // log2(10.66) = 3.41414351

    const int j0 = jb * jchunk;
#pragma unroll 4
    for (int jj = 0; jj < jchunk; ++jj) {
        const int j = j0 + jj;
        const float xj = state[j * 4 + 0];   // wave-uniform -> s_load
        const float yj = state[j * 4 + 1];
#pragma unroll
        for (int m = 0; m < 4; ++m) {
            const float dx  = xi[m] - xj;
            const float dy  = yi[m] - yj;
            const float r2  = fmaf(dx, dx, fmaf(dy, dy, EPS));
            const float inv = rsqrtf(r2);        // 1/d
            const float d   = r2 * inv;          // d = sqrt(r2)
            const float coef = exp2f(fmaf(d, -C1, C0)) * inv;
            // i == j: dx = dy = 0 -> contribution exactly 0 (coef finite), matches eye-mask
            fx[m] = fmaf(coef, dx, fx[m]);
            fy[m] = fmaf(coef, dy, fy[m]);
        }
    }

#pragma unroll
    for (int m = 0; m < 4; ++m) {
        const int i = ib * 1024 + m * 256 + tid;
        part[((size_t)jb * N + i) * 2 + 0] = fx[m];
        part[((size_t)jb * N + i) * 2 + 1] = fy[m];
    }
}

// ---------------------------------------------------------------------------
// Kernel 2: reduce partials, attraction force, propagation, cost.
// grid = 16, block = 256 (one thread per agent). Thread 0 of each block
// recomputes agent 0's new pose (cheap) so cost needs no third kernel.
// ---------------------------------------------------------------------------
__global__ __launch_bounds__(256) void finalize(const float* __restrict__ state,
                                                const float* __restrict__ cost_in,
                                                const float* __restrict__ goals,
                                                const float* __restrict__ rip,
                                                const float* __restrict__ obs,
                                                const float* __restrict__ part,
                                                float* __restrict__ out,
                                                int nbj) {
    __shared__ float s_p0[2];
    const int tid = threadIdx.x;
    const int i   = blockIdx.x * 256 + tid;

    if (tid == 0) {
        float fx = 0.f, fy = 0.f;
        for (int k = 0; k < nbj; ++k) {
            fx += part[((size_t)k * N) * 2 + 0];
            fy += part[((size_t)k * N) * 2 + 1];
        }
        const float px = state[0], py = state[1], vx = state[2], vy = state[3];
        const float gx = goals[0] - px, gy = goals[1] - py;
        const float gd = sqrtf(fmaf(gx, gx, fmaf(gy, gy, EPS)));
        fx += 120.f * (1.34f * gx / gd - vx);   // K*MASS = 120
        fy += 120.f * (1.34f * gy / gd - vy);
        float vnx = vx + fx * (0.4f / 60.f);
        float vny = vy + fy * (0.4f / 60.f);
        const float sp  = sqrtf(fmaf(vnx, vnx, fmaf(vny, vny, EPS)));
        const float fac = fminf(1.f, 1.34f / sp);
        vnx *= fac; vny *= fac;
        s_p0[0] = fmaf(vnx, 0.4f, px);
        s_p0[1] = fmaf(vny, 0.4f, py);
    }
    __syncthreads();

    float fx = 0.f, fy = 0.f;
    for (int k = 0; k < nbj; ++k) {
        fx += part[((size_t)k * N + i) * 2 + 0];
        fy += part[((size_t)k * N + i) * 2 + 1];
    }

    const float px = state[i * 4 + 0], py = state[i * 4 + 1];
    const float vx = state[i * 4 + 2], vy = state[i * 4 + 3];
    const float gx = goals[i * 2 + 0] - px, gy = goals[i * 2 + 1] - py;
    const float gd = sqrtf(fmaf(gx, gx, fmaf(gy, gy, EPS)));
    fx += 120.f * (1.34f * gx / gd - vx);
    fy += 120.f * (1.34f * gy / gd - vy);

    float vnx = vx + fx * (0.4f / 60.f);
    float vny = vy + fy * (0.4f / 60.f);
    const float sp  = sqrtf(fmaf(vnx, vnx, fmaf(vny, vny, EPS)));
    const float fac = fminf(1.f, 1.34f / sp);
    vnx *= fac; vny *= fac;
    const float pnx = fmaf(vnx, 0.4f, px);
    const float pny = fmaf(vny, 0.4f, py);

    out[i * 4 + 0] = pnx;
    out[i * 4 + 1] = pny;
    out[i * 4 + 2] = vnx;
    out[i * 4 + 3] = vny;

    // cost: -pg + blame + dev + cost_in
    const float rx = rip[0], ry = rip[1];
    const float gvx = goals[0] - rx, gvy = goals[1] - ry;
    const float p0x = s_p0[0], p0y = s_p0[1];
    const float pg = ((p0x - rx) * gvx + (p0y - ry) * gvy)
                   / (sqrtf(gvx * gvx + gvy * gvy) + EPS);
    const float ddx = pnx - p0x, ddy = pny - p0y;
    const float dist_rp = sqrtf(fmaf(ddx, ddx, fmaf(ddy, ddy, EPS)));
    const float blame = __expf(-dist_rp);
    const float ox = obs[i * 4 + 0], oy = obs[i * 4 + 1];
    const float dev = (pnx - ox) * (pnx - ox) + (pny - oy) * (pny - oy);

    out[4 * N + i] = cost_in[i] + (-pg + blame + dev);
}

extern "C" void kernel_launch(void* const* d_in, const int* in_sizes, int n_in,
                              void* d_out, int out_size, void* d_ws, size_t ws_size,
                              hipStream_t stream) {
    const float* state = (const float*)d_in[0];
    const float* cost  = (const float*)d_in[1];
    const float* goals = (const float*)d_in[2];
    const float* rip   = (const float*)d_in[3];
    const float* obs   = (const float*)d_in[4];
    float* out  = (float*)d_out;
    float* part = (float*)d_ws;

    int nbj = 128;  // 4 MB partials; shrink if workspace is smaller
    while (nbj > 1 && (size_t)nbj * N * 2 * sizeof(float) > ws_size) nbj >>= 1;
    const int jchunk = N / nbj;

    rep_partial<<<dim3(4, nbj), 256, 0, stream>>>(state, part, jchunk);
    finalize<<<16, 256, 0, stream>>>(state, cost, goals, rip, obs, part, out, nbj);
}

// Round 2
// 76.964 us; speedup vs baseline: 1.7230x; 1.7230x over previous
//
#include <hip/hip_runtime.h>

#define N 4096
#define EPS 1e-8f

// ---------------------------------------------------------------------------
// Kernel 1: partial repulsive forces, j-tile staged in LDS (N-body pattern).
// grid = (4, nbj), block = 256. Each thread owns 4 i's in registers (ILP to
// hide rsqrt/exp latency). LDS reads are wave-broadcast (same address all
// lanes -> conflict-free). Native v_rsq_f32 / v_exp_f32 via builtins.
// part layout: [nbj][N] float2 in d_ws.
// ---------------------------------------------------------------------------
__global__ __launch_bounds__(256) void rep_partial(const float2* __restrict__ state2,
                                                   float2* __restrict__ part,
                                                   int jchunk) {
    __shared__ float2 sj[256];
    const int tid = threadIdx.x;
    const int ib  = blockIdx.x;   // 0..3
    const int jb  = blockIdx.y;   // 0..nbj-1
    const int j0  = jb * jchunk;

    if (tid < jchunk) sj[tid] = state2[(j0 + tid) * 2];   // (x,y) of agent j

    float xi[4], yi[4], fx[4], fy[4];
#pragma unroll
    for (int m = 0; m < 4; ++m) {
        const int i = ib * 1024 + m * 256 + tid;
        const float2 p = state2[i * 2];
        xi[m] = p.x; yi[m] = p.y;
        fx[m] = 0.f; fy[m] = 0.f;
    }
    __syncthreads();

    // mag/dist = ALPHA * exp((2R - d)/BETTA) / d = exp2(C0 - C1*d) / d
    const float C1 = 1.44269504088896340736f / 0.71f;     // log2e / BETTA
    const float C0 = 0.6f * C1 + 3.41414351f;             // 2R*C1 + log2(ALPHA)

#pragma unroll 4
    for (int jj = 0; jj < jchunk; ++jj) {
        const float2 pj = sj[jj];
#pragma unroll
        for (int m = 0; m < 4; ++m) {
            const float dx   = xi[m] - pj.x;
            const float dy   = yi[m] - pj.y;
            const float r2   = fmaf(dx, dx, fmaf(dy, dy, EPS));
            const float inv  = __builtin_amdgcn_rsqf(r2);     // v_rsq_f32
            const float d    = r2 * inv;                      // sqrt(r2)
            const float coef = __builtin_amdgcn_exp2f(fmaf(d, -C1, C0)) * inv;
            // i == j: dx = dy = 0 -> contribution exactly 0, matches eye-mask
            fx[m] = fmaf(coef, dx, fx[m]);
            fy[m] = fmaf(coef, dy, fy[m]);
        }
    }

#pragma unroll
    for (int m = 0; m < 4; ++m) {
        const int i = ib * 1024 + m * 256 + tid;
        part[(size_t)jb * N + i] = make_float2(fx[m], fy[m]);
    }
}

// ---------------------------------------------------------------------------
// Kernel 2: parallel reduction of partials + attraction + propagation.
// grid = N/32 = 128 blocks, 256 threads: 32 i's x 8 k-slices per block.
// Coalesced: fixed k, 32 consecutive i -> 256B contiguous per slice-row.
// ---------------------------------------------------------------------------
__global__ __launch_bounds__(256) void reduce_prop(const float* __restrict__ state,
                                                   const float* __restrict__ goals,
                                                   const float2* __restrict__ part,
                                                   float* __restrict__ out,
                                                   int nbj) {
    __shared__ float2 red[256];
    const int tid = threadIdx.x;
    const int il  = tid & 31;          // i within block
    const int ks  = tid >> 5;          // k-slice 0..7
    const int i   = blockIdx.x * 32 + il;
    const int kper = nbj >> 3;

    float fx = 0.f, fy = 0.f;
    for (int k = ks * kper; k < ks * kper + kper; ++k) {
        const float2 p = part[(size_t)k * N + i];
        fx += p.x; fy += p.y;
    }
    red[tid] = make_float2(fx, fy);
    __syncthreads();

    if (ks == 0) {
#pragma unroll
        for (int s = 1; s < 8; ++s) {
            fx += red[s * 32 + il].x;
            fy += red[s * 32 + il].y;
        }
        const float px = state[i * 4 + 0], py = state[i * 4 + 1];
        const float vx = state[i * 4 + 2], vy = state[i * 4 + 3];
        const float gx = goals[i * 2 + 0] - px, gy = goals[i * 2 + 1] - py;
        const float gd = sqrtf(fmaf(gx, gx, fmaf(gy, gy, EPS)));
        fx += 120.f * (1.34f * gx / gd - vx);      // K*MASS = 120
        fy += 120.f * (1.34f * gy / gd - vy);
        float vnx = fmaf(fx, 0.4f / 60.f, vx);
        float vny = fmaf(fy, 0.4f / 60.f, vy);
        const float sp  = sqrtf(fmaf(vnx, vnx, fmaf(vny, vny, EPS)));
        const float fac = fminf(1.f, 1.34f / sp);
        vnx *= fac; vny *= fac;
        out[i * 4 + 0] = fmaf(vnx, 0.4f, px);
        out[i * 4 + 1] = fmaf(vny, 0.4f, py);
        out[i * 4 + 2] = vnx;
        out[i * 4 + 3] = vny;
    }
}

// ---------------------------------------------------------------------------
// Kernel 3: cost. Reads new state (incl. agent 0's pose, uniform) from out.
// ---------------------------------------------------------------------------
__global__ __launch_bounds__(256) void cost_k(const float* __restrict__ cost_in,
                                              const float* __restrict__ goals,
                                              const float* __restrict__ rip,
                                              const float* __restrict__ obs,
                                              const float* __restrict__ new_state,
                                              float* __restrict__ cost_out) {
    const int i = blockIdx.x * 256 + threadIdx.x;
    const float rx = rip[0], ry = rip[1];
    const float gvx = goals[0] - rx, gvy = goals[1] - ry;
    const float p0x = new_state[0], p0y = new_state[1];
    const float pg = ((p0x - rx) * gvx + (p0y - ry) * gvy)
                   / (sqrtf(gvx * gvx + gvy * gvy) + EPS);
    const float pnx = new_state[i * 4 + 0], pny = new_state[i * 4 + 1];
    const float ddx = pnx - p0x, ddy = pny - p0y;
    const float dist_rp = sqrtf(fmaf(ddx, ddx, fmaf(ddy, ddy, EPS)));
    const float blame = expf(-dist_rp);
    const float ox = obs[i * 4 + 0], oy = obs[i * 4 + 1];
    const float dev = (pnx - ox) * (pnx - ox) + (pny - oy) * (pny - oy);
    cost_out[i] = cost_in[i] + (-pg + blame + dev);
}

extern "C" void kernel_launch(void* const* d_in, const int* in_sizes, int n_in,
                              void* d_out, int out_size, void* d_ws, size_t ws_size,
                              hipStream_t stream) {
    const float* state = (const float*)d_in[0];
    const float* cost  = (const float*)d_in[1];
    const float* goals = (const float*)d_in[2];
    const float* rip   = (const float*)d_in[3];
    const float* obs   = (const float*)d_in[4];
    float* out  = (float*)d_out;
    float2* part = (float2*)d_ws;

    int nbj = 128;  // 4 MB partials; shrink if workspace is smaller
    while (nbj > 8 && (size_t)nbj * N * sizeof(float2) > ws_size) nbj >>= 1;
    const int jchunk = N / nbj;   // 32 at nbj=128 (<=256 always)

    rep_partial<<<dim3(4, nbj), 256, 0, stream>>>((const float2*)state, part, jchunk);
    reduce_prop<<<N / 32, 256, 0, stream>>>(state, goals, part, out, nbj);
    cost_k<<<N / 256, 256, 0, stream>>>(cost, goals, rip, obs, out, out + 4 * N);
}

// Round 3
// 76.363 us; speedup vs baseline: 1.7365x; 1.0079x over previous
//
#include <hip/hip_runtime.h>

#define N 4096
#define EPS 1e-8f

// ---------------------------------------------------------------------------
// Kernel 1: partial repulsive forces — occupancy-first version.
// grid = (16, 128) = 2048 blocks, 256 threads: 8 blocks/CU = 8 waves/SIMD
// (light ~30-VGPR body), so rsq/exp latency is hidden by TLP, not unroll ILP.
// Thread (i, jb) accumulates i's force over j in [jb*32, jb*32+32).
// part layout: [128][N] float2 in d_ws (coalesced 8B/lane writes).
// ---------------------------------------------------------------------------
__global__ __launch_bounds__(256) void rep_pairs(const float4* __restrict__ state4,
                                                 float2* __restrict__ part) {
    __shared__ float2 sj[32];
    const int tid = threadIdx.x;
    const int jb  = blockIdx.y;          // 0..127
    const int i   = blockIdx.x * 256 + tid;

    if (tid < 32) {
        const float4 s = state4[jb * 32 + tid];
        sj[tid] = make_float2(s.x, s.y);
    }
    const float4 si = state4[i];
    const float xi = si.x, yi = si.y;
    __syncthreads();

    // mag/dist = ALPHA * exp((2R - d)/BETTA) / d = exp2(C0 - C1*d) / d
    const float C1 = 1.44269504088896340736f / 0.71f;   // log2e / BETTA
    const float C0 = 0.6f * C1 + 3.41414351f;           // 2R*C1 + log2(ALPHA)

    float fx0 = 0.f, fy0 = 0.f, fx1 = 0.f, fy1 = 0.f;
#pragma unroll 4
    for (int jj = 0; jj < 32; jj += 2) {
        {
            const float2 pj = sj[jj];
            const float dx   = xi - pj.x;
            const float dy   = yi - pj.y;
            const float r2   = fmaf(dx, dx, fmaf(dy, dy, EPS));
            const float inv  = __builtin_amdgcn_rsqf(r2);
            const float d    = r2 * inv;
            const float coef = __builtin_amdgcn_exp2f(fmaf(d, -C1, C0)) * inv;
            fx0 = fmaf(coef, dx, fx0);   // i==j: dx=dy=0 -> exact 0 contribution
            fy0 = fmaf(coef, dy, fy0);
        }
        {
            const float2 pj = sj[jj + 1];
            const float dx   = xi - pj.x;
            const float dy   = yi - pj.y;
            const float r2   = fmaf(dx, dx, fmaf(dy, dy, EPS));
            const float inv  = __builtin_amdgcn_rsqf(r2);
            const float d    = r2 * inv;
            const float coef = __builtin_amdgcn_exp2f(fmaf(d, -C1, C0)) * inv;
            fx1 = fmaf(coef, dx, fx1);
            fy1 = fmaf(coef, dy, fy1);
        }
    }
    part[(size_t)jb * N + i] = make_float2(fx0 + fx1, fy0 + fy1);
}

// ---------------------------------------------------------------------------
// Kernel 2: parallel reduction of partials + attraction + propagation.
// grid = N/32 = 128 blocks, 256 threads: 32 i's x 8 k-slices per block.
// ---------------------------------------------------------------------------
__global__ __launch_bounds__(256) void reduce_prop(const float* __restrict__ state,
                                                   const float* __restrict__ goals,
                                                   const float2* __restrict__ part,
                                                   float* __restrict__ out,
                                                   int nbj) {
    __shared__ float2 red[256];
    const int tid = threadIdx.x;
    const int il  = tid & 31;          // i within block
    const int ks  = tid >> 5;          // k-slice 0..7
    const int i   = blockIdx.x * 32 + il;
    const int kper = nbj >> 3;

    float fx = 0.f, fy = 0.f;
    for (int k = ks * kper; k < ks * kper + kper; ++k) {
        const float2 p = part[(size_t)k * N + i];
        fx += p.x; fy += p.y;
    }
    red[tid] = make_float2(fx, fy);
    __syncthreads();

    if (ks == 0) {
#pragma unroll
        for (int s = 1; s < 8; ++s) {
            fx += red[s * 32 + il].x;
            fy += red[s * 32 + il].y;
        }
        const float px = state[i * 4 + 0], py = state[i * 4 + 1];
        const float vx = state[i * 4 + 2], vy = state[i * 4 + 3];
        const float gx = goals[i * 2 + 0] - px, gy = goals[i * 2 + 1] - py;
        const float gd = sqrtf(fmaf(gx, gx, fmaf(gy, gy, EPS)));
        fx += 120.f * (1.34f * gx / gd - vx);      // K*MASS = 120
        fy += 120.f * (1.34f * gy / gd - vy);
        float vnx = fmaf(fx, 0.4f / 60.f, vx);
        float vny = fmaf(fy, 0.4f / 60.f, vy);
        const float sp  = sqrtf(fmaf(vnx, vnx, fmaf(vny, vny, EPS)));
        const float fac = fminf(1.f, 1.34f / sp);
        vnx *= fac; vny *= fac;
        out[i * 4 + 0] = fmaf(vnx, 0.4f, px);
        out[i * 4 + 1] = fmaf(vny, 0.4f, py);
        out[i * 4 + 2] = vnx;
        out[i * 4 + 3] = vny;
    }
}

// ---------------------------------------------------------------------------
// Kernel 3: cost. Reads new state (incl. agent 0's pose, uniform) from out.
// ---------------------------------------------------------------------------
__global__ __launch_bounds__(256) void cost_k(const float* __restrict__ cost_in,
                                              const float* __restrict__ goals,
                                              const float* __restrict__ rip,
                                              const float* __restrict__ obs,
                                              const float* __restrict__ new_state,
                                              float* __restrict__ cost_out) {
    const int i = blockIdx.x * 256 + threadIdx.x;
    const float rx = rip[0], ry = rip[1];
    const float gvx = goals[0] - rx, gvy = goals[1] - ry;
    const float p0x = new_state[0], p0y = new_state[1];
    const float pg = ((p0x - rx) * gvx + (p0y - ry) * gvy)
                   / (sqrtf(gvx * gvx + gvy * gvy) + EPS);
    const float pnx = new_state[i * 4 + 0], pny = new_state[i * 4 + 1];
    const float ddx = pnx - p0x, ddy = pny - p0y;
    const float dist_rp = sqrtf(fmaf(ddx, ddx, fmaf(ddy, ddy, EPS)));
    const float blame = expf(-dist_rp);
    const float ox = obs[i * 4 + 0], oy = obs[i * 4 + 1];
    const float dev = (pnx - ox) * (pnx - ox) + (pny - oy) * (pny - oy);
    cost_out[i] = cost_in[i] + (-pg + blame + dev);
}

extern "C" void kernel_launch(void* const* d_in, const int* in_sizes, int n_in,
                              void* d_out, int out_size, void* d_ws, size_t ws_size,
                              hipStream_t stream) {
    const float* state = (const float*)d_in[0];
    const float* cost  = (const float*)d_in[1];
    const float* goals = (const float*)d_in[2];
    const float* rip   = (const float*)d_in[3];
    const float* obs   = (const float*)d_in[4];
    float* out  = (float*)d_out;
    float2* part = (float2*)d_ws;

    const int nbj = 128;   // 4 MB partials in d_ws

    rep_pairs<<<dim3(16, nbj), 256, 0, stream>>>((const float4*)state, part);
    reduce_prop<<<N / 32, 256, 0, stream>>>(state, goals, part, out, nbj);
    cost_k<<<N / 256, 256, 0, stream>>>(cost, goals, rip, obs, out, out + 4 * N);
}

// Round 4
// 70.334 us; speedup vs baseline: 1.8854x; 1.0857x over previous
//
#include <hip/hip_runtime.h>

#define N 4096
#define NBJ 64          // j-chunks; partials = NBJ*N*8B = 2 MB in d_ws
#define EPS 1e-8f

// ---------------------------------------------------------------------------
// Kernel 1: partial repulsive forces.
// grid = (16, NBJ) = 1024 blocks, 256 threads -> 4 waves/SIMD.
// Thread (i, jb) accumulates i's force over 64 j's staged in LDS.
// Issue model: ~11 VALU (2 of them trans) per pair -> ~3.6 us whole-kernel.
// ---------------------------------------------------------------------------
__global__ __launch_bounds__(256) void rep_pairs(const float4* __restrict__ state4,
                                                 float2* __restrict__ part) {
    __shared__ float2 sj[64];
    const int tid = threadIdx.x;
    const int jb  = blockIdx.y;               // 0..NBJ-1
    const int i   = blockIdx.x * 256 + tid;   // 0..4095

    if (tid < 64) {
        const float4 s = state4[jb * 64 + tid];
        sj[tid] = make_float2(s.x, s.y);
    }
    const float4 si = state4[i];
    const float xi = si.x, yi = si.y;
    __syncthreads();

    // mag/dist = ALPHA * exp((2R - d)/BETTA) / d = exp2(C0 - C1*d) / d
    const float C1 = 1.44269504088896340736f / 0.71f;   // log2e / BETTA
    const float C0 = 0.6f * C1 + 3.41414351f;           // 2R*C1 + log2(ALPHA)

    float fx0 = 0.f, fy0 = 0.f, fx1 = 0.f, fy1 = 0.f;
#pragma unroll 8
    for (int jj = 0; jj < 64; jj += 2) {
        {
            const float2 pj = sj[jj];
            const float dx   = xi - pj.x;
            const float dy   = yi - pj.y;
            const float r2   = fmaf(dx, dx, fmaf(dy, dy, EPS));
            const float inv  = __builtin_amdgcn_rsqf(r2);
            const float d    = r2 * inv;
            const float coef = __builtin_amdgcn_exp2f(fmaf(d, -C1, C0)) * inv;
            fx0 = fmaf(coef, dx, fx0);   // i==j: dx=dy=0 -> exact 0, matches eye-mask
            fy0 = fmaf(coef, dy, fy0);
        }
        {
            const float2 pj = sj[jj + 1];
            const float dx   = xi - pj.x;
            const float dy   = yi - pj.y;
            const float r2   = fmaf(dx, dx, fmaf(dy, dy, EPS));
            const float inv  = __builtin_amdgcn_rsqf(r2);
            const float d    = r2 * inv;
            const float coef = __builtin_amdgcn_exp2f(fmaf(d, -C1, C0)) * inv;
            fx1 = fmaf(coef, dx, fx1);
            fy1 = fmaf(coef, dy, fy1);
        }
    }
    part[(size_t)jb * N + i] = make_float2(fx0 + fx1, fy0 + fy1);
}

// ---------------------------------------------------------------------------
// Kernel 2 (fused): reduce partials + attraction + propagation + cost.
// grid = N/128 = 32 blocks, 256 threads: il = t&127 (i), ks = t>>7 (k half).
// Wave 0 additionally shuffle-reduces agent 0's force and propagates it to
// s_p0 so the cost term needs no extra kernel.
// ---------------------------------------------------------------------------
__global__ __launch_bounds__(256) void finalize(const float* __restrict__ state,
                                                const float* __restrict__ cost_in,
                                                const float* __restrict__ goals,
                                                const float* __restrict__ rip,
                                                const float4* __restrict__ obs4,
                                                const float2* __restrict__ part,
                                                float* __restrict__ out) {
    __shared__ float2 red[2][128];
    __shared__ float2 s_p0;
    const int tid = threadIdx.x;
    const int il  = tid & 127;
    const int ks  = tid >> 7;                 // 0 or 1
    const int i   = blockIdx.x * 128 + il;

    float fx = 0.f, fy = 0.f;
    for (int k = ks * 32; k < ks * 32 + 32; ++k) {
        const float2 p = part[(size_t)k * N + i];
        fx += p.x; fy += p.y;
    }
    red[ks][il] = make_float2(fx, fy);

    // wave 0: reduce agent 0's NBJ=64 partials across 64 lanes, propagate.
    if (tid < 64) {
        float2 f0 = part[(size_t)tid * N + 0];
#pragma unroll
        for (int off = 32; off > 0; off >>= 1) {
            f0.x += __shfl_down(f0.x, off);
            f0.y += __shfl_down(f0.y, off);
        }
        if (tid == 0) {
            const float px = state[0], py = state[1], vx = state[2], vy = state[3];
            const float gx = goals[0] - px, gy = goals[1] - py;
            const float gd = sqrtf(fmaf(gx, gx, fmaf(gy, gy, EPS)));
            const float Fx = f0.x + 120.f * (1.34f * gx / gd - vx);
            const float Fy = f0.y + 120.f * (1.34f * gy / gd - vy);
            float vnx = fmaf(Fx, 0.4f / 60.f, vx);
            float vny = fmaf(Fy, 0.4f / 60.f, vy);
            const float sp  = sqrtf(fmaf(vnx, vnx, fmaf(vny, vny, EPS)));
            const float fac = fminf(1.f, 1.34f / sp);
            vnx *= fac; vny *= fac;
            s_p0 = make_float2(fmaf(vnx, 0.4f, px), fmaf(vny, 0.4f, py));
        }
    }
    __syncthreads();

    if (ks == 0) {
        fx += red[1][il].x;
        fy += red[1][il].y;

        const float px = state[i * 4 + 0], py = state[i * 4 + 1];
        const float vx = state[i * 4 + 2], vy = state[i * 4 + 3];
        const float gx = goals[i * 2 + 0] - px, gy = goals[i * 2 + 1] - py;
        const float gd = sqrtf(fmaf(gx, gx, fmaf(gy, gy, EPS)));
        fx += 120.f * (1.34f * gx / gd - vx);      // K*MASS = 120
        fy += 120.f * (1.34f * gy / gd - vy);
        float vnx = fmaf(fx, 0.4f / 60.f, vx);
        float vny = fmaf(fy, 0.4f / 60.f, vy);
        const float sp  = sqrtf(fmaf(vnx, vnx, fmaf(vny, vny, EPS)));
        const float fac = fminf(1.f, 1.34f / sp);
        vnx *= fac; vny *= fac;
        const float pnx = fmaf(vnx, 0.4f, px);
        const float pny = fmaf(vny, 0.4f, py);

        out[i * 4 + 0] = pnx;
        out[i * 4 + 1] = pny;
        out[i * 4 + 2] = vnx;
        out[i * 4 + 3] = vny;

        // cost = cost_in - pg + blame + dev
        const float rx = rip[0], ry = rip[1];
        const float gvx = goals[0] - rx, gvy = goals[1] - ry;
        const float p0x = s_p0.x, p0y = s_p0.y;
        const float pg = ((p0x - rx) * gvx + (p0y - ry) * gvy)
                       / (sqrtf(gvx * gvx + gvy * gvy) + EPS);
        const float ddx = pnx - p0x, ddy = pny - p0y;
        const float dist_rp = sqrtf(fmaf(ddx, ddx, fmaf(ddy, ddy, EPS)));
        const float blame = __expf(-dist_rp);
        const float4 ob = obs4[i];
        const float dev = (pnx - ob.x) * (pnx - ob.x) + (pny - ob.y) * (pny - ob.y);

        out[4 * N + i] = cost_in[i] + (-pg + blame + dev);
    }
}

extern "C" void kernel_launch(void* const* d_in, const int* in_sizes, int n_in,
                              void* d_out, int out_size, void* d_ws, size_t ws_size,
                              hipStream_t stream) {
    const float* state = (const float*)d_in[0];
    const float* cost  = (const float*)d_in[1];
    const float* goals = (const float*)d_in[2];
    const float* rip   = (const float*)d_in[3];
    const float* obs   = (const float*)d_in[4];
    float* out   = (float*)d_out;
    float2* part = (float2*)d_ws;   // 2 MB

    rep_pairs<<<dim3(16, NBJ), 256, 0, stream>>>((const float4*)state, part);
    finalize<<<N / 128, 256, 0, stream>>>(state, cost, goals, rip,
                                          (const float4*)state == nullptr ? nullptr : (const float4*)d_in[4],
                                          part, out);
}